// Round 4
// baseline (74.841 us; speedup 1.0000x reference)
//
#include <hip/hip_runtime.h>

#define INF   256   // input features
#define OUTF  128   // NUM_HEADS * HEAD_DIM
#define WROWS 32    // output rows per wave (2 MFMA row-tiles)

typedef __attribute__((ext_vector_type(8))) short bf16x8;
typedef __attribute__((ext_vector_type(4))) float f32x4;

__device__ __forceinline__ ushort f2bf(float f) {
    unsigned u = __float_as_uint(f);
    u += 0x7FFFu + ((u >> 16) & 1u);   // round-to-nearest-even
    return (ushort)(u >> 16);
}

// ---------------------------------------------------------------------------
__global__ __launch_bounds__(256) void wbf_kernel(const float* __restrict__ W,
                                                  ushort* __restrict__ Wbf) {
    int t = blockIdx.x * 256 + threadIdx.x;
    if (t < OUTF * INF) Wbf[t] = f2bf(W[t]);
}

// flags[dst] = 1 (racy identical stores: benign). flags 100 KB -> L2.
__global__ __launch_bounds__(256) void mark_kernel(const int* __restrict__ dst,
                                                   unsigned char* __restrict__ flags,
                                                   int E) {
    int e = blockIdx.x * 256 + threadIdx.x;
    if (e < E) flags[dst[e]] = 1;
}

// ---------------------------------------------------------------------------
// out = flag ? elu(x @ W^T) : 0, bf16 MFMA. Barrier-free, LDS-free dataflow:
// each wave owns 32 rows x 128 cols; A-frags straight from global x (fp32 ->
// bf16 in regs), B-frags re-read from 64KB L1/L2-resident Wbf each k-step.
// Fragment scheme (verified passing in R3): A row=lane&15, k=(lane>>4)*8+j;
// B col=lane&15, same k; D col=lane&15, row=(lane>>4)*4+j.
__global__ __launch_bounds__(256) void gemm_fused(const float* __restrict__ x,
        const ushort* __restrict__ Wbf, const unsigned char* __restrict__ flags,
        float* __restrict__ out, int nrows) {
    const int t    = threadIdx.x;
    const int lane = t & 63;
    const int wid  = blockIdx.x * 4 + (t >> 6);
    const int row0 = wid * WROWS;
    if (row0 >= nrows) return;
    const bool full = (row0 + WROWS <= nrows);

    const int rlo = lane & 15;     // row-in-tile (A) / col-in-tile (B,D)
    const int kg  = lane >> 4;     // k-group: 8 contiguous k each

    f32x4 acc[2][8];
#pragma unroll
    for (int rt = 0; rt < 2; ++rt)
#pragma unroll
        for (int ct = 0; ct < 8; ++ct)
            acc[rt][ct] = (f32x4){0.f, 0.f, 0.f, 0.f};

#pragma unroll
    for (int ks = 0; ks < 8; ++ks) {
        // A fragments: 2 row-tiles, 8 fp32 each from x, convert to bf16
        bf16x8 af[2];
#pragma unroll
        for (int rt = 0; rt < 2; ++rt) {
            int r = row0 + rt * 16 + rlo;
            if (!full && r >= nrows) r = nrows - 1;   // harmless clamp
            const float* px = x + (size_t)r * INF + ks * 32 + kg * 8;
            float4 v0 = *reinterpret_cast<const float4*>(px);
            float4 v1 = *reinterpret_cast<const float4*>(px + 4);
            union { ushort s[8]; bf16x8 v; } ua;
            ua.s[0] = f2bf(v0.x); ua.s[1] = f2bf(v0.y);
            ua.s[2] = f2bf(v0.z); ua.s[3] = f2bf(v0.w);
            ua.s[4] = f2bf(v1.x); ua.s[5] = f2bf(v1.y);
            ua.s[6] = f2bf(v1.z); ua.s[7] = f2bf(v1.w);
            af[rt] = ua.v;
        }
        // B fragments from L1/L2-resident Wbf + MFMAs
#pragma unroll
        for (int ct = 0; ct < 8; ++ct) {
            uint4 raw = *reinterpret_cast<const uint4*>(
                Wbf + (size_t)(ct * 16 + rlo) * INF + ks * 32 + kg * 8);
            bf16x8 bf = __builtin_bit_cast(bf16x8, raw);
            acc[0][ct] = __builtin_amdgcn_mfma_f32_16x16x32_bf16(af[0], bf, acc[0][ct], 0, 0, 0);
            acc[1][ct] = __builtin_amdgcn_mfma_f32_16x16x32_bf16(af[1], bf, acc[1][ct], 0, 0, 0);
        }
    }

    // Epilogue: D col = lane&15, row = kg*4 + j; flag-gated elu
#pragma unroll
    for (int rt = 0; rt < 2; ++rt) {
#pragma unroll
        for (int j = 0; j < 4; ++j) {
            int r = row0 + rt * 16 + kg * 4 + j;
            if (!full && r >= nrows) continue;
            const bool fl = flags[r] != 0;
            float* orow = out + (size_t)r * OUTF + rlo;
#pragma unroll
            for (int ct = 0; ct < 8; ++ct) {
                float v = acc[rt][ct][j];
                float o = 0.f;
                if (fl) o = v > 0.f ? v : (__expf(v) - 1.f);
                orow[ct * 16] = o;
            }
        }
    }
}

// ---------------------------------------------------------------------------
extern "C" void kernel_launch(void* const* d_in, const int* in_sizes, int n_in,
                              void* d_out, int out_size, void* d_ws, size_t ws_size,
                              hipStream_t stream) {
    const float* x  = (const float*)d_in[0];
    const int*   ei = (const int*)d_in[1];
    const float* W  = (const float*)d_in[3];
    float* out = (float*)d_out;

    const int n = in_sizes[0] / INF;   // 100000 nodes
    const int E = in_sizes[1] / 2;     // 1600000 edges

    ushort* Wbf          = (ushort*)d_ws;                         // 65536 B
    unsigned char* flags = (unsigned char*)((char*)d_ws + 65536); // n bytes

    hipMemsetAsync(flags, 0, (size_t)n, stream);
    wbf_kernel<<<(OUTF * INF + 255) / 256, 256, 0, stream>>>(W, Wbf);
    mark_kernel<<<(E + 255) / 256, 256, 0, stream>>>(ei + E, flags, E);

    const int nwaves  = (n + WROWS - 1) / WROWS;   // 3125
    const int nblocks = (nwaves + 3) / 4;          // 782
    gemm_fused<<<nblocks, 256, 0, stream>>>(x, Wbf, flags, out, n);
}